// Round 9
// baseline (219.439 us; speedup 1.0000x reference)
//
#include <hip/hip_runtime.h>
#include <hip/hip_bf16.h>

#define B_  8
#define N_  2048
#define KD_ 256
#define AD_ 128
#define VD_ 256
#define SQL2E 1.2011224087864498f   // sqrt(log2(e)); folded into proj so attn uses exp2

using s16x8 = __attribute__((ext_vector_type(8))) short;
using f16x8 = __attribute__((ext_vector_type(8))) _Float16;
using h2    = __attribute__((ext_vector_type(2))) __fp16;
using f32x4 = __attribute__((ext_vector_type(4))) float;

__device__ __forceinline__ f32x4 mfma16(s16x8 a, s16x8 b, f32x4 c) {
  return __builtin_amdgcn_mfma_f32_16x16x32_f16(
      __builtin_bit_cast(f16x8, a), __builtin_bit_cast(f16x8, b), c, 0, 0, 0);
}
__device__ __forceinline__ short f2h(float f) {
  _Float16 h = (_Float16)f;
  return *reinterpret_cast<short*>(&h);
}
// raw hardware exp2 (v_exp_f32): 1 VALU op (libm exp2f takes the OCML precise
// path, ~6-8 ops -- measured regression R6/R7).
__device__ __forceinline__ float exp2_hw(float x) {
#if __has_builtin(__builtin_amdgcn_exp2f)
  return __builtin_amdgcn_exp2f(x);
#else
  float r;
  asm volatile("v_exp_f32 %0, %1" : "=v"(r) : "v"(x));
  return r;
#endif
}
__device__ __forceinline__ s16x8 cvt8(const float* __restrict__ p) {
  union { s16x8 v; h2 h[4]; } u;
  f32x4 a = *(const f32x4*)p;
  f32x4 bq = *(const f32x4*)(p + 4);
  u.h[0] = __builtin_amdgcn_cvt_pkrtz(a[0], a[1]);
  u.h[1] = __builtin_amdgcn_cvt_pkrtz(a[2], a[3]);
  u.h[2] = __builtin_amdgcn_cvt_pkrtz(bq[0], bq[1]);
  u.h[3] = __builtin_amdgcn_cvt_pkrtz(bq[2], bq[3]);
  return u.v;
}

// ---------------- fused prep (unchanged from R8) ----------------------------
__global__ __launch_bounds__(256) void prep_k(
    const float* __restrict__ k1, const float* __restrict__ k2,
    const float* __restrict__ v1, const float* __restrict__ v2,
    const float* __restrict__ W1, const float* __restrict__ b1f,
    const float* __restrict__ W2, const float* __restrict__ b2f,
    short* __restrict__ q1p, short* __restrict__ q2p,
    short* __restrict__ vt1, short* __restrict__ vt2) {
  __shared__ __align__(16) short sWT[128 * 264];   // proj role only
  const int t  = threadIdx.x;
  const int id = blockIdx.x;

  if (id < 512) {
    const int kt = id & 31, b = (id >> 5) & 7, z = id >> 8;
    const float* src = z ? v2 : v1;
    short*       dst = z ? vt2 : vt1;
    const size_t base = ((size_t)(b * 32 + kt)) * (256 * 64);
    const int w = t >> 6, vchunk = (t >> 4) & 3, l16 = t & 15;
    #pragma unroll
    for (int i = 0; i < 8; i++) {
      float x[8];
      #pragma unroll
      for (int kk = 0; kk < 8; kk++)
        x[kk] = src[((size_t)(b * N_ + kt * 64 + i * 8 + kk)) * VD_ + t];
      union { s16x8 v; h2 h[4]; } u;
      #pragma unroll
      for (int kk = 0; kk < 4; kk++)
        u.h[kk] = __builtin_amdgcn_cvt_pkrtz(x[2 * kk], x[2 * kk + 1]);
      int f = vchunk * 2 + (i >> 2);
      *(s16x8*)&dst[base + (size_t)((w * 8 + f) * 64 + (i & 3) * 16 + l16) * 8] = u.v;
    }
    return;
  }

  const int pid = id - 512;
  const int z = pid >> 8, mb = pid & 255;
  const float* X    = z ? k2 : k1;
  const float* W    = z ? W2 : W1;
  const float* bias = z ? b2f : b1f;
  short*       Y    = z ? q2p : q1p;
  const int m0   = mb * 64;
  const int lane = t & 63, wave = t >> 6, quad = lane >> 4, l16 = lane & 15;

  #pragma unroll
  for (int j = 0; j < 64; j++) {
    int idx = j * 256 + t;
    int n = idx & 127, kh = idx >> 7;
    h2 p = __builtin_amdgcn_cvt_pkrtz(W[(size_t)(2 * kh) * AD_ + n] * SQL2E,
                                      W[(size_t)(2 * kh + 1) * AD_ + n] * SQL2E);
    *(h2*)&sWT[n * 264 + kh * 2] = p;
  }
  const float* xrow = &X[(size_t)(m0 + wave * 16 + l16) * KD_];
  s16x8 a[8];
  #pragma unroll
  for (int ks = 0; ks < 8; ks++) a[ks] = cvt8(xrow + ks * 32 + quad * 8);
  __syncthreads();

  f32x4 acc[8];
  #pragma unroll
  for (int nt = 0; nt < 8; nt++) acc[nt] = (f32x4){0.f, 0.f, 0.f, 0.f};
  #pragma unroll
  for (int ks = 0; ks < 8; ks++) {
    #pragma unroll
    for (int nt = 0; nt < 8; nt++) {
      s16x8 bf = *(const s16x8*)&sWT[(nt * 16 + l16) * 264 + ks * 32 + quad * 8];
      acc[nt] = mfma16(a[ks], bf, acc[nt]);
    }
  }
  #pragma unroll
  for (int nt = 0; nt < 8; nt++) {
    float bv = bias[nt * 16 + l16] * SQL2E;
    #pragma unroll
    for (int r = 0; r < 4; r++) {
      int row = m0 + wave * 16 + quad * 4 + r;
      Y[(size_t)row * AD_ + nt * 16 + l16] = f2h(acc[nt][r] + bv);
    }
  }
}

// ---------------- flash attention: q32 x k-split, 4 blocks/CU ---------------
// Block: 32 q-rows, 4 waves. Wave w: q-half qh=w&1 (16 rows), k-half kh=w>>1
// (32 keys of the 64-key tile): 8 QK MFMA. PV v-split: wave w covers all 32 q
// x v-cols [w*64, w*64+64): 16 MFMA, acc 8xf32x4. Pair (qh, kh^1) unifies the
// softmax max via LDS; defer-max decisions are pair-uniform by construction.
// 2 barriers/iter; grid 1024 -> 4 blocks/CU (2x TLP vs R8).
__global__ __launch_bounds__(256, 4) void attn_k(
    const short* __restrict__ q1p, const short* __restrict__ q2p,
    const short* __restrict__ vt1, const short* __restrict__ vt2,
    float* __restrict__ out) {
  __shared__ __align__(16) short sK[2][64 * 136];  // 34816 B
  __shared__ __align__(16) short sP[4][16 * 40];   //  5120 B (80 B rows, swz)
  __shared__ __align__(16) float sM[64];           // half-max / epilogue lf
  __shared__ __align__(16) float sAl[32];          // alpha per q-row / final l
  __shared__ __align__(16) float sFl[4];           // rescale flags per q-half

  const int t    = threadIdx.x;
  const int lane = t & 63, wave = t >> 6, quad = lane >> 4, l16 = lane & 15;
  const int qh   = wave & 1, kh = wave >> 1;
  // XCD-aware decode (1024 % 8 == 0, bijective): each XCD owns 2 (b,pass).
  const int id   = blockIdx.x;
  const int xcd  = id & 7, seq = id >> 3;
  const int bp   = xcd * 2 + (seq >> 6);
  const int qb   = seq & 63;
  const int b    = bp & 7, pass = bp >> 3;
  const int q0   = qb * 32;
  const short* Q  = pass ? q2p : q1p;
  const short* K  = pass ? q1p : q2p;
  const short* Vt = pass ? vt1 : vt2;
  float* O = out + (size_t)pass * ((size_t)B_ * N_ * VD_);

  const short* kp = K + (size_t)(b * N_) * AD_ + (size_t)(t >> 4) * AD_ + (t & 15) * 8;
  const short* vp = Vt + (size_t)b * 32 * (256 * 64) + wave * 4096 + lane * 8;

  s16x8 qf[4];
  #pragma unroll
  for (int ks = 0; ks < 4; ks++)
    qf[ks] = *(const s16x8*)&Q[((size_t)(b * N_ + q0 + qh * 16 + l16)) * AD_ +
                               ks * 32 + quad * 8];

  float m_i = -1e30f, l_i = 0.f;   // log2 domain; l_i quad+khalf partial
  f32x4 acc[8];                    // [m*4+v]: q-tile m (0,1) x v-16tile v
  #pragma unroll
  for (int c0 = 0; c0 < 8; c0++) acc[c0] = (f32x4){0.f, 0.f, 0.f, 0.f};

  s16x8 pk[4], pv[8];
  auto loadK = [&]() {
    #pragma unroll
    for (int i = 0; i < 4; i++) pk[i] = *(const s16x8*)(kp + i * 16 * AD_);
    kp += 64 * AD_;
  };
  auto loadV = [&]() {
    #pragma unroll
    for (int f = 0; f < 8; f++) pv[f] = *(const s16x8*)(vp + f * 512);
    vp += 256 * 64;
  };
  auto storeK = [&](int cb) {
    #pragma unroll
    for (int i = 0; i < 4; i++) {
      int chunk = i * 256 + t, row = chunk >> 4, c8 = chunk & 15;
      *(s16x8*)&sK[cb][row * 136 + c8 * 8] = pk[i];
    }
  };

  // prologue: sK[0] <- K(0); pk <- K(1); pv <- V(0)
  loadK(); storeK(0); loadK(); loadV();
  __syncthreads();

  for (int kt = 0; kt < 32; kt++) {
    const int c = kt & 1;
    // QK(kt), own k-half: st[nt][r] = S[key = kh*32+nt*16+quad*4+r][q]
    f32x4 st[2];
    st[0] = (f32x4){0.f, 0.f, 0.f, 0.f};
    st[1] = (f32x4){0.f, 0.f, 0.f, 0.f};
    __builtin_amdgcn_s_setprio(1);
    #pragma unroll
    for (int ks = 0; ks < 4; ks++) {
      #pragma unroll
      for (int nt = 0; nt < 2; nt++) {
        s16x8 kf = *(const s16x8*)&sK[c][(kh * 32 + nt * 16 + l16) * 136 +
                                         ks * 32 + quad * 8];
        st[nt] = mfma16(kf, qf[ks], st[nt]);
      }
    }
    __builtin_amdgcn_s_setprio(0);

    // half-tile max (8 in-lane) + quad combine; publish for the pair
    float a0 = fmaxf(st[0][0], st[1][0]), a1 = fmaxf(st[0][1], st[1][1]);
    float a2 = fmaxf(st[0][2], st[1][2]), a3 = fmaxf(st[0][3], st[1][3]);
    float hm = fmaxf(fmaxf(a0, a1), fmaxf(a2, a3));
    hm = fmaxf(hm, __shfl_xor(hm, 16));
    hm = fmaxf(hm, __shfl_xor(hm, 32));
    if (quad == 0) sM[wave * 16 + l16] = hm;

    if (kt + 1 < 32) storeK(1 - c);
    __syncthreads();                               // A: sM + sK(kt+1) ready
    if (kt + 2 < 32) loadK();

    // unify max with partner k-half (identical result on both waves)
    float pm = sM[(wave ^ 2) * 16 + l16];
    float mt = fmaxf(hm, pm);
    float alpha = 1.f;
    bool  resc  = !__all(mt - m_i <= 8.f);         // pair-uniform
    if (resc) {
      float mn = fmaxf(m_i, mt);
      alpha = exp2_hw(m_i - mn);
      l_i *= alpha;
      m_i  = mn;
    }
    f32x4 psv = (f32x4){0.f, 0.f, 0.f, 0.f};
    #pragma unroll
    for (int nt = 0; nt < 2; nt++) {
      #pragma unroll
      for (int r = 0; r < 4; r++) {
        float p = exp2_hw(st[nt][r] - m_i);
        st[nt][r] = p;
        psv[r] += p;
      }
    }
    l_i += (psv[0] + psv[1]) + (psv[2] + psv[3]);

    // write P half (16q x 32k) to own region; 8B chunks, XOR-swizzled
    #pragma unroll
    for (int nt = 0; nt < 2; nt++) {
      union { h2 h[2]; uint2 u; } wu;
      wu.h[0] = __builtin_amdgcn_cvt_pkrtz(st[nt][0], st[nt][1]);
      wu.h[1] = __builtin_amdgcn_cvt_pkrtz(st[nt][2], st[nt][3]);
      int cpw = (nt * 4 + quad) ^ ((l16 & 3) << 1);
      *(uint2*)&sP[wave][l16 * 40 + cpw * 4] = wu.u;
    }
    if (wave < 2 && quad == 0) sAl[wave * 16 + l16] = alpha;
    if (wave < 2 && lane == 0) sFl[wave] = resc ? 1.f : 0.f;
    __syncthreads();                               // B: sP/sAl/sFl ready

    // cross-wave acc rescale (rare)
    float f0 = sFl[0], f1 = sFl[1];
    if (f0 + f1 != 0.f) {
      #pragma unroll
      for (int m = 0; m < 2; m++) {
        f32x4 aR = *(const f32x4*)&sAl[m * 16 + quad * 4];
        #pragma unroll
        for (int v = 0; v < 4; v++) {
          #pragma unroll
          for (int r = 0; r < 4; r++) acc[m * 4 + v][r] *= aR[r];
        }
      }
    }

    // PV(kt): af from region (qh=m, kh=ks2) = wave ks2*2+m; bf in registers
    __builtin_amdgcn_s_setprio(1);
    #pragma unroll
    for (int m = 0; m < 2; m++) {
      #pragma unroll
      for (int ks2 = 0; ks2 < 2; ks2++) {
        int cp = (2 * quad) ^ ((l16 & 3) << 1);    // even -> 16B aligned
        s16x8 af = *(const s16x8*)&sP[ks2 * 2 + m][l16 * 40 + cp * 4];
        #pragma unroll
        for (int v = 0; v < 4; v++)
          acc[m * 4 + v] = mfma16(af, pv[v * 2 + ks2], acc[m * 4 + v]);
      }
    }
    __builtin_amdgcn_s_setprio(0);

    if (kt + 1 < 32) loadV();
  }

  // epilogue: combine l over quads (shfl), then over k-half pair (LDS)
  float lf = l_i + __shfl_xor(l_i, 16);
  lf += __shfl_xor(lf, 32);
  if (quad == 0) sM[wave * 16 + l16] = lf;
  __syncthreads();
  if (wave < 2 && quad == 0)
    sAl[wave * 16 + l16] = sM[wave * 16 + l16] + sM[(wave + 2) * 16 + l16];
  __syncthreads();
  #pragma unroll
  for (int m = 0; m < 2; m++) {
    f32x4 lv = *(const f32x4*)&sAl[m * 16 + quad * 4];
    #pragma unroll
    for (int r = 0; r < 4; r++) {
      float inv = 1.f / lv[r];
      int row = q0 + m * 16 + quad * 4 + r;
      #pragma unroll
      for (int v = 0; v < 4; v++)
        O[((size_t)(b * N_ + row)) * VD_ + wave * 64 + v * 16 + l16] =
            acc[m * 4 + v][r] * inv;
    }
  }
}

extern "C" void kernel_launch(void* const* d_in, const int* in_sizes, int n_in,
                              void* d_out, int out_size, void* d_ws, size_t ws_size,
                              hipStream_t stream) {
  const float* k1 = (const float*)d_in[0];
  const float* k2 = (const float*)d_in[1];
  const float* v1 = (const float*)d_in[2];
  const float* v2 = (const float*)d_in[3];
  const float* W1 = (const float*)d_in[4];
  const float* b1 = (const float*)d_in[5];
  const float* W2 = (const float*)d_in[6];
  const float* b2 = (const float*)d_in[7];

  short* ws  = (short*)d_ws;
  short* q1p = ws;                                   // 16384*128 f16 (4 MB)
  short* q2p = q1p + (size_t)16384 * 128;
  short* vt1 = q2p + (size_t)16384 * 128;            // 8*32*256*64 f16 (8.4 MB)
  short* vt2 = vt1 + (size_t)B_ * 32 * 256 * 64;
  float* out = (float*)d_out;

  prep_k<<<dim3(1024), dim3(256), 0, stream>>>(k1, k2, v1, v2, W1, b1, W2, b2,
                                               q1p, q2p, vt1, vt2);
  attn_k<<<dim3(1024), dim3(256), 0, stream>>>(q1p, q2p, vt1, vt2, out);
}

// Round 10
// 179.849 us; speedup vs baseline: 1.2201x; 1.2201x over previous
//
#include <hip/hip_runtime.h>
#include <hip/hip_bf16.h>

#define B_  8
#define N_  2048
#define KD_ 256
#define AD_ 128
#define VD_ 256
#define SQL2E 1.2011224087864498f   // sqrt(log2(e)); folded into proj so attn uses exp2

using s16x8 = __attribute__((ext_vector_type(8))) short;
using f16x8 = __attribute__((ext_vector_type(8))) _Float16;
using h2    = __attribute__((ext_vector_type(2))) __fp16;
using f32x4 = __attribute__((ext_vector_type(4))) float;

__device__ __forceinline__ f32x4 mfma16(s16x8 a, s16x8 b, f32x4 c) {
  return __builtin_amdgcn_mfma_f32_16x16x32_f16(
      __builtin_bit_cast(f16x8, a), __builtin_bit_cast(f16x8, b), c, 0, 0, 0);
}
__device__ __forceinline__ short f2h(float f) {
  _Float16 h = (_Float16)f;
  return *reinterpret_cast<short*>(&h);
}
// raw hardware exp2 (v_exp_f32): 1 VALU op (libm exp2f takes the OCML precise
// path, ~6-8 ops -- measured regression R6/R7).
__device__ __forceinline__ float exp2_hw(float x) {
#if __has_builtin(__builtin_amdgcn_exp2f)
  return __builtin_amdgcn_exp2f(x);
#else
  float r;
  asm volatile("v_exp_f32 %0, %1" : "=v"(r) : "v"(x));
  return r;
#endif
}
__device__ __forceinline__ s16x8 cvt8(const float* __restrict__ p) {
  union { s16x8 v; h2 h[4]; } u;
  f32x4 a = *(const f32x4*)p;
  f32x4 bq = *(const f32x4*)(p + 4);
  u.h[0] = __builtin_amdgcn_cvt_pkrtz(a[0], a[1]);
  u.h[1] = __builtin_amdgcn_cvt_pkrtz(a[2], a[3]);
  u.h[2] = __builtin_amdgcn_cvt_pkrtz(bq[0], bq[1]);
  u.h[3] = __builtin_amdgcn_cvt_pkrtz(bq[2], bq[3]);
  return u.v;
}

// ---------------- fused prep (unchanged from R8) ----------------------------
__global__ __launch_bounds__(256) void prep_k(
    const float* __restrict__ k1, const float* __restrict__ k2,
    const float* __restrict__ v1, const float* __restrict__ v2,
    const float* __restrict__ W1, const float* __restrict__ b1f,
    const float* __restrict__ W2, const float* __restrict__ b2f,
    short* __restrict__ q1p, short* __restrict__ q2p,
    short* __restrict__ vt1, short* __restrict__ vt2) {
  __shared__ __align__(16) short sWT[128 * 264];   // proj role only
  const int t  = threadIdx.x;
  const int id = blockIdx.x;

  if (id < 512) {
    const int kt = id & 31, b = (id >> 5) & 7, z = id >> 8;
    const float* src = z ? v2 : v1;
    short*       dst = z ? vt2 : vt1;
    const size_t base = ((size_t)(b * 32 + kt)) * (256 * 64);
    const int w = t >> 6, vchunk = (t >> 4) & 3, l16 = t & 15;
    #pragma unroll
    for (int i = 0; i < 8; i++) {
      float x[8];
      #pragma unroll
      for (int kk = 0; kk < 8; kk++)
        x[kk] = src[((size_t)(b * N_ + kt * 64 + i * 8 + kk)) * VD_ + t];
      union { s16x8 v; h2 h[4]; } u;
      #pragma unroll
      for (int kk = 0; kk < 4; kk++)
        u.h[kk] = __builtin_amdgcn_cvt_pkrtz(x[2 * kk], x[2 * kk + 1]);
      int f = vchunk * 2 + (i >> 2);
      *(s16x8*)&dst[base + (size_t)((w * 8 + f) * 64 + (i & 3) * 16 + l16) * 8] = u.v;
    }
    return;
  }

  const int pid = id - 512;
  const int z = pid >> 8, mb = pid & 255;
  const float* X    = z ? k2 : k1;
  const float* W    = z ? W2 : W1;
  const float* bias = z ? b2f : b1f;
  short*       Y    = z ? q2p : q1p;
  const int m0   = mb * 64;
  const int lane = t & 63, wave = t >> 6, quad = lane >> 4, l16 = lane & 15;

  #pragma unroll
  for (int j = 0; j < 64; j++) {
    int idx = j * 256 + t;
    int n = idx & 127, kh = idx >> 7;
    h2 p = __builtin_amdgcn_cvt_pkrtz(W[(size_t)(2 * kh) * AD_ + n] * SQL2E,
                                      W[(size_t)(2 * kh + 1) * AD_ + n] * SQL2E);
    *(h2*)&sWT[n * 264 + kh * 2] = p;
  }
  const float* xrow = &X[(size_t)(m0 + wave * 16 + l16) * KD_];
  s16x8 a[8];
  #pragma unroll
  for (int ks = 0; ks < 8; ks++) a[ks] = cvt8(xrow + ks * 32 + quad * 8);
  __syncthreads();

  f32x4 acc[8];
  #pragma unroll
  for (int nt = 0; nt < 8; nt++) acc[nt] = (f32x4){0.f, 0.f, 0.f, 0.f};
  #pragma unroll
  for (int ks = 0; ks < 8; ks++) {
    #pragma unroll
    for (int nt = 0; nt < 8; nt++) {
      s16x8 bf = *(const s16x8*)&sWT[(nt * 16 + l16) * 264 + ks * 32 + quad * 8];
      acc[nt] = mfma16(a[ks], bf, acc[nt]);
    }
  }
  #pragma unroll
  for (int nt = 0; nt < 8; nt++) {
    float bv = bias[nt * 16 + l16] * SQL2E;
    #pragma unroll
    for (int r = 0; r < 4; r++) {
      int row = m0 + wave * 16 + quad * 4 + r;
      Y[(size_t)row * AD_ + nt * 16 + l16] = f2h(acc[nt][r] + bv);
    }
  }
}

// ---------------- flash attention: K-quarter in registers, no sK ------------
// Wave w owns keys [w*16, w*16+16) of each 64-key tile, held in 4 s16x8 regs
// streamed from L2-hot global one window ahead. QK(i) = pure-register MFMA
// (zero LDS). Softmax max unified across quarters via sMt (publish pre-
// barrier, read post-barrier). PV runs ONE WINDOW BEHIND: window i does
// [QK(i), publish] -> barrier -> [loadK(i+1), rescale(alpha(i-1)), PV(i-1),
// loadV(i), softmax(i) -> write sP/sAl]. One barrier/iter; sP/sMt/sAl
// double-buffered, every cross-wave use separated by >= 1 barrier.
__global__ __launch_bounds__(256, 2) void attn_k(
    const short* __restrict__ q1p, const short* __restrict__ q2p,
    const short* __restrict__ vt1, const short* __restrict__ vt2,
    float* __restrict__ out) {
  __shared__ __align__(16) short sP[2][64 * 64];    // 16384 B, XOR-swizzled
  __shared__ __align__(16) float sMt[2][4][16][4];  // [c][wave][l16][qt] 2 KB
  __shared__ __align__(16) float sAl[2][64];        // alpha per q (resc only)
  __shared__ __align__(16) float sL[64];            // epilogue 1/l

  const int t    = threadIdx.x;
  const int lane = t & 63, wave = t >> 6, quad = lane >> 4, l16 = lane & 15;
  const int id   = blockIdx.x;
  const int xcd  = id & 7, seq = id >> 3;
  const int bp   = xcd * 2 + (seq >> 5);
  const int qb   = seq & 31;
  const int b    = bp & 7, pass = bp >> 3;
  const int q0   = qb * 64;
  const short* Q  = pass ? q2p : q1p;
  const short* K  = pass ? q1p : q2p;
  const short* Vt = pass ? vt1 : vt2;
  float* O = out + (size_t)pass * ((size_t)B_ * N_ * VD_);

  // K quarter pointer: lane (quad,l16) of wave -> key row wave*16+l16,
  // d-chunk quad*8 (A-frag layout directly from global)
  const short* kp = K + ((size_t)(b * N_) + wave * 16 + l16) * AD_ + quad * 8;
  const short* vp = Vt + (size_t)b * 32 * (256 * 64) + wave * 4096 + lane * 8;

  // Q fragments (loop-invariant, 64 VGPR): qf[qt][ks]
  s16x8 qf[4][4];
  #pragma unroll
  for (int qt = 0; qt < 4; qt++)
    #pragma unroll
    for (int ks = 0; ks < 4; ks++)
      qf[qt][ks] = *(const s16x8*)&Q[((size_t)(b * N_ + q0 + qt * 16 + l16)) * AD_ +
                                     ks * 32 + quad * 8];

  f32x4 m4 = (f32x4){-1e30f, -1e30f, -1e30f, -1e30f};   // per-qt running max (log2)
  f32x4 l4 = (f32x4){0.f, 0.f, 0.f, 0.f};               // per-qt partial l
  f32x4 acc[16];
  #pragma unroll
  for (int c0 = 0; c0 < 16; c0++) acc[c0] = (f32x4){0.f, 0.f, 0.f, 0.f};

  s16x8 kf[4], pv[8];
  auto loadK = [&]() {
    #pragma unroll
    for (int ks = 0; ks < 4; ks++) kf[ks] = *(const s16x8*)(kp + ks * 32);
    kp += 64 * AD_;
  };
  auto loadV = [&]() {
    #pragma unroll
    for (int f = 0; f < 8; f++) pv[f] = *(const s16x8*)(vp + f * 512);
    vp += 256 * 64;
  };

  loadK();   // kf <- K(0)
  loadV();   // pv <- V(0)

  f32x4 stq[4];
  bool prevResc = false;

  for (int i = 0; i <= 32; i++) {
    const int c = i & 1;
    if (i < 32) {
      // QK(i): S[key = wave*16+quad*4+r][q = qt*16+l16], pure registers
      #pragma unroll
      for (int qt = 0; qt < 4; qt++) stq[qt] = (f32x4){0.f, 0.f, 0.f, 0.f};
      __builtin_amdgcn_s_setprio(1);
      #pragma unroll
      for (int ks = 0; ks < 4; ks++) {
        #pragma unroll
        for (int qt = 0; qt < 4; qt++)
          stq[qt] = mfma16(kf[ks], qf[qt][ks], stq[qt]);
      }
      __builtin_amdgcn_s_setprio(0);

      // per-qt quarter max: in-lane over 4 keys + cross-quad combine
      float hm0 = fmaxf(fmaxf(stq[0][0], stq[0][1]), fmaxf(stq[0][2], stq[0][3]));
      float hm1 = fmaxf(fmaxf(stq[1][0], stq[1][1]), fmaxf(stq[1][2], stq[1][3]));
      float hm2 = fmaxf(fmaxf(stq[2][0], stq[2][1]), fmaxf(stq[2][2], stq[2][3]));
      float hm3 = fmaxf(fmaxf(stq[3][0], stq[3][1]), fmaxf(stq[3][2], stq[3][3]));
      hm0 = fmaxf(hm0, __shfl_xor(hm0, 16)); hm0 = fmaxf(hm0, __shfl_xor(hm0, 32));
      hm1 = fmaxf(hm1, __shfl_xor(hm1, 16)); hm1 = fmaxf(hm1, __shfl_xor(hm1, 32));
      hm2 = fmaxf(hm2, __shfl_xor(hm2, 16)); hm2 = fmaxf(hm2, __shfl_xor(hm2, 32));
      hm3 = fmaxf(hm3, __shfl_xor(hm3, 16)); hm3 = fmaxf(hm3, __shfl_xor(hm3, 32));
      if (quad == 0) {
        f32x4 hv = (f32x4){hm0, hm1, hm2, hm3};
        *(f32x4*)&sMt[c][wave][l16][0] = hv;
      }
    }

    __syncthreads();
    if (i + 1 < 32) loadK();           // kf <- K(i+1); drains at barrier(i+1)

    if (i > 0) {
      const int cprev = 1 - c;
      // rescale acc by alpha(i-1) BEFORE adding P(i-1)V(i-1) (rare path)
      if (prevResc) {
        #pragma unroll
        for (int m = 0; m < 4; m++) {
          f32x4 aR = *(const f32x4*)&sAl[cprev][m * 16 + quad * 4];
          #pragma unroll
          for (int v = 0; v < 4; v++) {
            #pragma unroll
            for (int r = 0; r < 4; r++) acc[m * 4 + v][r] *= aR[r];
          }
        }
      }
      // PV(i-1): af from sP[cprev] (written last window), V in registers
      __builtin_amdgcn_s_setprio(1);
      #pragma unroll
      for (int m = 0; m < 4; m++) {
        #pragma unroll
        for (int ks2 = 0; ks2 < 2; ks2++) {
          int physr = (ks2 * 8 + quad * 2) ^ ((l16 & 7) << 1);
          s16x8 af = *(const s16x8*)&sP[cprev][(m * 16 + l16) * 64 + physr * 4];
          #pragma unroll
          for (int v = 0; v < 4; v++)
            acc[m * 4 + v] = mfma16(af, pv[v * 2 + ks2], acc[m * 4 + v]);
        }
      }
      __builtin_amdgcn_s_setprio(0);
      if (i < 32) loadV();             // pv <- V(i) for PV(i) next window
    }

    if (i < 32) {
      // unified tile max across the 4 key-quarters (identical on all waves)
      f32x4 w0 = *(const f32x4*)&sMt[c][0][l16][0];
      f32x4 w1 = *(const f32x4*)&sMt[c][1][l16][0];
      f32x4 w2 = *(const f32x4*)&sMt[c][2][l16][0];
      f32x4 w3 = *(const f32x4*)&sMt[c][3][l16][0];
      f32x4 mt4;
      #pragma unroll
      for (int qt = 0; qt < 4; qt++)
        mt4[qt] = fmaxf(fmaxf(w0[qt], w1[qt]), fmaxf(w2[qt], w3[qt]));

      // defer-max (log2 units, P <= 2^8): decision wave-uniform & identical
      bool ok = (mt4[0] - m4[0] <= 8.f) && (mt4[1] - m4[1] <= 8.f) &&
                (mt4[2] - m4[2] <= 8.f) && (mt4[3] - m4[3] <= 8.f);
      bool resc = !__all(ok);
      if (resc) {
        f32x4 al;
        #pragma unroll
        for (int qt = 0; qt < 4; qt++) {
          float mn = fmaxf(m4[qt], mt4[qt]);
          al[qt]  = exp2_hw(m4[qt] - mn);
          m4[qt]  = mn;
          l4[qt] *= al[qt];
        }
        if (wave == 0 && quad == 0) {
          #pragma unroll
          for (int qt = 0; qt < 4; qt++) sAl[c][qt * 16 + l16] = al[qt];
        }
      }
      prevResc = resc;

      // exps + partial sums + pack -> sP[c] (read next window, post-barrier)
      #pragma unroll
      for (int qt = 0; qt < 4; qt++) {
        float p0 = exp2_hw(stq[qt][0] - m4[qt]);
        float p1 = exp2_hw(stq[qt][1] - m4[qt]);
        float p2 = exp2_hw(stq[qt][2] - m4[qt]);
        float p3 = exp2_hw(stq[qt][3] - m4[qt]);
        l4[qt] += (p0 + p1) + (p2 + p3);
        union { h2 h[2]; uint2 u; } wu;
        wu.h[0] = __builtin_amdgcn_cvt_pkrtz(p0, p1);
        wu.h[1] = __builtin_amdgcn_cvt_pkrtz(p2, p3);
        int phys = (wave * 4 + quad) ^ ((l16 & 7) << 1);
        *(uint2*)&sP[c][(qt * 16 + l16) * 64 + phys * 4] = wu.u;
      }
    }
  }

  // epilogue: l over quads (shfl) -> per-wave quarters -> sum via LDS
  #pragma unroll
  for (int qt = 0; qt < 4; qt++) {
    l4[qt] += __shfl_xor(l4[qt], 16);
    l4[qt] += __shfl_xor(l4[qt], 32);
  }
  if (quad == 0) *(f32x4*)&sMt[0][wave][l16][0] = l4;
  __syncthreads();
  if (wave == 0 && quad == 0) {
    f32x4 s0 = *(const f32x4*)&sMt[0][0][l16][0];
    f32x4 s1 = *(const f32x4*)&sMt[0][1][l16][0];
    f32x4 s2 = *(const f32x4*)&sMt[0][2][l16][0];
    f32x4 s3 = *(const f32x4*)&sMt[0][3][l16][0];
    #pragma unroll
    for (int qt = 0; qt < 4; qt++)
      sL[qt * 16 + l16] = 1.f / (s0[qt] + s1[qt] + s2[qt] + s3[qt]);
  }
  __syncthreads();
  #pragma unroll
  for (int m = 0; m < 4; m++) {
    f32x4 lv = *(const f32x4*)&sL[m * 16 + quad * 4];
    #pragma unroll
    for (int r = 0; r < 4; r++) {
      int row = q0 + m * 16 + quad * 4 + r;
      #pragma unroll
      for (int v = 0; v < 4; v++)
        O[((size_t)(b * N_ + row)) * VD_ + wave * 64 + v * 16 + l16] =
            acc[m * 4 + v][r] * lv[r];
    }
  }
}

extern "C" void kernel_launch(void* const* d_in, const int* in_sizes, int n_in,
                              void* d_out, int out_size, void* d_ws, size_t ws_size,
                              hipStream_t stream) {
  const float* k1 = (const float*)d_in[0];
  const float* k2 = (const float*)d_in[1];
  const float* v1 = (const float*)d_in[2];
  const float* v2 = (const float*)d_in[3];
  const float* W1 = (const float*)d_in[4];
  const float* b1 = (const float*)d_in[5];
  const float* W2 = (const float*)d_in[6];
  const float* b2 = (const float*)d_in[7];

  short* ws  = (short*)d_ws;
  short* q1p = ws;                                   // 16384*128 f16 (4 MB)
  short* q2p = q1p + (size_t)16384 * 128;
  short* vt1 = q2p + (size_t)16384 * 128;            // 8*32*256*64 f16 (8.4 MB)
  short* vt2 = vt1 + (size_t)B_ * 32 * 256 * 64;
  float* out = (float*)d_out;

  prep_k<<<dim3(1024), dim3(256), 0, stream>>>(k1, k2, v1, v2, W1, b1, W2, b2,
                                               q1p, q2p, vt1, vt2);
  attn_k<<<dim3(512), dim3(256), 0, stream>>>(q1p, q2p, vt1, vt2, out);
}